// Round 2
// baseline (2572.920 us; speedup 1.0000x reference)
//
#include <hip/hip_runtime.h>
#include <hip/hip_fp16.h>

#define OT_B 64
#define OT_N 512
#define OT_M 512
#define OT_ITERS 50
#define OT_STAB 1e-8f
#define OT_NWG 8                    // workgroups cooperating per batch
#define OT_ROWS (OT_N / OT_NWG)     // 64 rows owned per WG

// ---------------- Kernel 1: K = exp(-C/eps) in fp16 ----------------
__global__ __launch_bounds__(256) void ot_precompute_K(const float* __restrict__ C,
                                                       __half2* __restrict__ K2, int total2) {
    int stride = gridDim.x * blockDim.x;
    const float2* C2 = (const float2*)C;
    for (int i = blockIdx.x * blockDim.x + threadIdx.x; i < total2; i += stride) {
        float2 c = C2[i];
        K2[i] = __floats2half2_rn(expf(-20.0f * c.x), expf(-20.0f * c.y));
    }
}

// ---------------- group spin barrier (8 WGs of one batch) ----------------
__device__ __forceinline__ void group_barrier(int* cnt, int target) {
    __syncthreads();
    if (threadIdx.x == 0) {
        __hip_atomic_fetch_add(cnt, 1, __ATOMIC_RELEASE, __HIP_MEMORY_SCOPE_AGENT);
        while (__hip_atomic_load(cnt, __ATOMIC_RELAXED, __HIP_MEMORY_SCOPE_AGENT) < target)
            __builtin_amdgcn_s_sleep(4);
        __threadfence();   // acquire: invalidate L1 before anyone reads exchanged data
    }
    __syncthreads();
}

// ---------------- Kernel 2: Sinkhorn, 8 WGs per batch ----------------
// PRE=true: K is precomputed fp16 in ws. PRE=false: recompute exp from C (fallback).
template <bool PRE>
__global__ __launch_bounds__(512) void ot_sinkhorn(const __half* __restrict__ K,
                                                   const float* __restrict__ Cg,
                                                   float* __restrict__ Pout,
                                                   float* __restrict__ lossOut,
                                                   float* __restrict__ partial, // [B][NWG][M]
                                                   float* __restrict__ u_ws,    // [B][N]
                                                   int* __restrict__ counters)  // [B][32]
{
    __shared__ float u_lds[OT_N];
    __shared__ float v_lds[OT_M];
    __shared__ float red[512];

    const int b = blockIdx.x & (OT_B - 1);   // batch
    const int g = blockIdx.x >> 6;           // group member 0..7 (same XCD as peers: (b+64g)%8==b%8)
    const int t = threadIdx.x;
    const int lane = t & 63;
    const int wv = t >> 6;                   // wave 0..7
    const int r0 = g * OT_ROWS;

    const size_t batchOff = (size_t)b * OT_N * OT_M;
    const __half* Kb = K + batchOff;
    const float* Cb = Cg + batchOff;
    float* part_b = partial + (size_t)b * OT_NWG * OT_M;
    float* u_b = u_ws + (size_t)b * OT_N;
    int* cnt = counters + b * 32;            // 128B-spaced to avoid false sharing

    int bphase = 0;

    u_lds[t] = 1.0f / OT_N;                  // u0 = 1/n
    __syncthreads();

    for (int it = 0; it < OT_ITERS; ++it) {
        // ---- Phase 1: partial column sums over own 64 rows; thread t owns column t ----
        float acc = 0.0f;
        if (PRE) {
            const __half* colp = Kb + (size_t)r0 * OT_M + t;
            #pragma unroll 32
            for (int i = 0; i < OT_ROWS; ++i)
                acc += __half2float(colp[(size_t)i * OT_M]) * u_lds[r0 + i];
        } else {
            const float* colp = Cb + (size_t)r0 * OT_M + t;
            #pragma unroll 8
            for (int i = 0; i < OT_ROWS; ++i)
                acc += __expf(-20.0f * colp[(size_t)i * OT_M]) * u_lds[r0 + i];
        }
        __hip_atomic_store(&part_b[g * OT_M + t], acc, __ATOMIC_RELAXED, __HIP_MEMORY_SCOPE_AGENT);

        ++bphase;
        group_barrier(cnt, OT_NWG * bphase);   // barrier A

        // ---- Phase 2a: v_j computed redundantly by every WG (saves a barrier) ----
        float s = OT_STAB;
        #pragma unroll
        for (int w = 0; w < OT_NWG; ++w)
            s += __hip_atomic_load(&part_b[w * OT_M + t], __ATOMIC_RELAXED, __HIP_MEMORY_SCOPE_AGENT);
        v_lds[t] = (1.0f / OT_M) / s;
        __syncthreads();

        // ---- Phase 2b: u_i for own rows; 8 waves x 8 rows, lane-coalesced ----
        for (int rr = wv; rr < OT_ROWS; rr += 8) {
            const int i = r0 + rr;
            float s0 = 0.0f;
            if (PRE) {
                const __half2* rowp = (const __half2*)(Kb + (size_t)i * OT_M);
                const float2* v2 = (const float2*)v_lds;
                #pragma unroll
                for (int k2 = 0; k2 < OT_M / 128; ++k2) {
                    int idx = lane + 64 * k2;
                    float2 f = __half22float2(rowp[idx]);
                    float2 vv = v2[idx];
                    s0 += f.x * vv.x + f.y * vv.y;
                }
            } else {
                const float* rowp = Cb + (size_t)i * OT_M;
                #pragma unroll
                for (int k = 0; k < OT_M / 64; ++k) {
                    int idx = lane + 64 * k;
                    s0 += __expf(-20.0f * rowp[idx]) * v_lds[idx];
                }
            }
            #pragma unroll
            for (int off = 32; off >= 1; off >>= 1)
                s0 += __shfl_xor(s0, off);
            if (lane == 0)
                __hip_atomic_store(&u_b[i], (1.0f / OT_N) / (s0 + OT_STAB),
                                   __ATOMIC_RELAXED, __HIP_MEMORY_SCOPE_AGENT);
        }

        ++bphase;
        group_barrier(cnt, OT_NWG * bphase);   // barrier B

        // reload full fresh u for next phase-1 / final pass
        u_lds[t] = __hip_atomic_load(&u_b[t], __ATOMIC_RELAXED, __HIP_MEMORY_SCOPE_AGENT);
        __syncthreads();
    }

    // ---- Final: P = u_i * K_ij * v_j and loss, over own 64 rows ----
    float lacc = 0.0f;
    for (int rr = 0; rr < OT_ROWS; ++rr) {
        const int i = r0 + rr;
        const size_t off = batchOff + (size_t)i * OT_M + t;
        float kv;
        if (PRE) kv = __half2float(K[off]);
        else     kv = __expf(-20.0f * Cg[off]);
        float p = u_lds[i] * kv * v_lds[t];
        Pout[off] = p;
        lacc += p * Cg[off];
    }
    red[t] = lacc;
    __syncthreads();
    #pragma unroll
    for (int sft = 256; sft >= 64; sft >>= 1) {
        if (t < sft) red[t] += red[t + sft];
        __syncthreads();
    }
    if (t < 64) {
        float rsum = red[t];
        #pragma unroll
        for (int off = 32; off >= 1; off >>= 1) rsum += __shfl_xor(rsum, off);
        if (t == 0) atomicAdd(&lossOut[b], rsum);
    }
}

extern "C" void kernel_launch(void* const* d_in, const int* in_sizes, int n_in,
                              void* d_out, int out_size, void* d_ws, size_t ws_size,
                              hipStream_t stream) {
    const float* C = (const float*)d_in[0];
    float* P = (float*)d_out;
    float* loss = (float*)d_out + (size_t)OT_B * OT_N * OT_M;

    // ws layout: small exchange buffers first (fallback-safe), then fp16 K
    size_t off = 0;
    float* partial = (float*)((char*)d_ws + off);
    off += (size_t)OT_B * OT_NWG * OT_M * sizeof(float);       // 1 MB
    float* u_ws = (float*)((char*)d_ws + off);
    off += (size_t)OT_B * OT_N * sizeof(float);                // 128 KB
    int* counters = (int*)((char*)d_ws + off);
    off += (size_t)OT_B * 32 * sizeof(int);                    // 8 KB
    off = (off + 255) & ~(size_t)255;
    __half* Kh = (__half*)((char*)d_ws + off);
    const size_t kElems = (size_t)OT_B * OT_N * OT_M;
    const size_t needed = off + kElems * sizeof(__half);       // ~34.7 MB

    hipMemsetAsync(counters, 0, (size_t)OT_B * 32 * sizeof(int), stream);
    hipMemsetAsync(loss, 0, (size_t)OT_B * sizeof(float), stream);

    if (ws_size >= needed) {
        ot_precompute_K<<<1024, 256, 0, stream>>>(C, (__half2*)Kh, (int)(kElems / 2));
        ot_sinkhorn<true><<<OT_B * OT_NWG, 512, 0, stream>>>(Kh, C, P, loss,
                                                             partial, u_ws, counters);
    } else {
        ot_sinkhorn<false><<<OT_B * OT_NWG, 512, 0, stream>>>(nullptr, C, P, loss,
                                                              partial, u_ws, counters);
    }
}

// Round 4
// 747.817 us; speedup vs baseline: 3.4406x; 3.4406x over previous
//
#include <hip/hip_runtime.h>
#include <hip/hip_fp16.h>

#define OT_B 64
#define OT_N 512
#define OT_M 512
#define OT_ITERS 50
#define OT_STAB 1e-8f
#define OT_NWG 4                    // workgroups cooperating per batch
#define OT_ROWS (OT_N / OT_NWG)     // 128 rows owned per WG
#define OT_T 1024                   // threads per WG

// ---------------- Kernel 1: K = exp(-C/eps) in fp16 ----------------
__global__ __launch_bounds__(256) void ot_precompute_K(const float* __restrict__ C,
                                                       __half2* __restrict__ K2, int total2) {
    int stride = gridDim.x * blockDim.x;
    const float2* C2 = (const float2*)C;
    for (int i = blockIdx.x * blockDim.x + threadIdx.x; i < total2; i += stride) {
        float2 c = C2[i];
        K2[i] = __floats2half2_rn(expf(-20.0f * c.x), expf(-20.0f * c.y));
    }
}

// ---------------- group barrier: release add + relaxed spin, NO cache fences ----
// All cross-WG data moves via agent-scope atomic ops (cache-bypassing), so no
// acquire-side invalidate is needed; the release on fetch_add orders our
// partial stores before the counter bump.
__device__ __forceinline__ void group_barrier(int* cnt, int target) {
    __syncthreads();
    if (threadIdx.x == 0) {
        __hip_atomic_fetch_add(cnt, 1, __ATOMIC_RELEASE, __HIP_MEMORY_SCOPE_AGENT);
        while (__hip_atomic_load(cnt, __ATOMIC_RELAXED, __HIP_MEMORY_SCOPE_AGENT) < target)
            __builtin_amdgcn_s_sleep(2);
        asm volatile("" ::: "memory");   // compiler barrier: no hoisting of data loads
    }
    __syncthreads();
}

// ---------------- Kernel 2: Sinkhorn, 4 WGs x 1024 threads per batch ----------
// PRE=true: K precomputed fp16 in ws. PRE=false: recompute exp from C.
template <bool PRE>
__global__ __launch_bounds__(1024) void ot_sinkhorn(const __half* __restrict__ K,
                                                    const float* __restrict__ Cg,
                                                    float* __restrict__ Pout,
                                                    float* __restrict__ lossOut,
                                                    float* __restrict__ partial, // [2][B][NWG][M]
                                                    int* __restrict__ counters)  // [B][32]
{
    __shared__ float u_lds[OT_ROWS];   // own rows only — never exchanged
    __shared__ float v_lds[OT_M];
    __shared__ float sp[OT_T];

    const int b = blockIdx.x & (OT_B - 1);   // batch
    const int g = blockIdx.x >> 6;           // group member 0..3 (same XCD: (b+64g)%8==b%8)
    const int t = threadIdx.x;
    const int lane = t & 63;
    const int wv = t >> 6;                   // wave 0..15
    const int j = t & (OT_M - 1);            // owned column (phase 1 / final)
    const int h = t >> 9;                    // row-half selector (0/1)
    const int r0 = g * OT_ROWS;

    const size_t batchOff = (size_t)b * OT_N * OT_M;
    const __half* Kb = K + batchOff;
    const float* Cb = Cg + batchOff;
    int* cnt = counters + b * 32;

    if (t < OT_ROWS) u_lds[t] = 1.0f / OT_N;
    __syncthreads();

    for (int it = 0; it < OT_ITERS; ++it) {
        float* buf = partial + ((size_t)(it & 1) * OT_B + b) * OT_NWG * OT_M;

        // ---- Phase 1: partial column sums over own rows. thread t: col j,
        //      rows [r0 + h*64, +64). Wave loads are 64 consecutive fp16 = 128B.
        float acc = 0.0f;
        {
            const float* up = &u_lds[h * (OT_ROWS / 2)];
            if (PRE) {
                const __half* colp = Kb + (size_t)(r0 + h * (OT_ROWS / 2)) * OT_M + j;
                #pragma unroll 16
                for (int i = 0; i < OT_ROWS / 2; ++i)
                    acc += __half2float(colp[(size_t)i * OT_M]) * up[i];
            } else {
                const float* colp = Cb + (size_t)(r0 + h * (OT_ROWS / 2)) * OT_M + j;
                #pragma unroll 8
                for (int i = 0; i < OT_ROWS / 2; ++i)
                    acc += __expf(-20.0f * colp[(size_t)i * OT_M]) * up[i];
            }
        }
        sp[t] = acc;
        __syncthreads();
        if (t < OT_M)
            __hip_atomic_store(&buf[g * OT_M + t], sp[t] + sp[t + OT_M],
                               __ATOMIC_RELAXED, __HIP_MEMORY_SCOPE_AGENT);

        group_barrier(cnt, OT_NWG * (it + 1));   // the ONLY barrier per iteration

        // ---- Phase 2a: v_j computed redundantly by every WG from the 4 partials ----
        if (t < OT_M) {
            float s = OT_STAB;
            #pragma unroll
            for (int w = 0; w < OT_NWG; ++w)
                s += __hip_atomic_load(&buf[w * OT_M + t], __ATOMIC_RELAXED,
                                       __HIP_MEMORY_SCOPE_AGENT);
            v_lds[t] = (1.0f / OT_M) / s;
        }
        __syncthreads();

        // ---- Phase 2b: u for own rows (local only). 16 waves x 8 rows. ----
        for (int rr = wv; rr < OT_ROWS; rr += 16) {
            float s0 = 0.0f;
            if (PRE) {
                const __half2* rowp = (const __half2*)(Kb + (size_t)(r0 + rr) * OT_M);
                const float2* v2 = (const float2*)v_lds;
                #pragma unroll
                for (int k = 0; k < OT_M / 128; ++k) {
                    int idx = lane + 64 * k;
                    float2 f = __half22float2(rowp[idx]);
                    float2 vv = v2[idx];
                    s0 += f.x * vv.x + f.y * vv.y;
                }
            } else {
                const float* rowp = Cb + (size_t)(r0 + rr) * OT_M;
                #pragma unroll
                for (int k = 0; k < OT_M / 64; ++k) {
                    int idx = lane + 64 * k;
                    s0 += __expf(-20.0f * rowp[idx]) * v_lds[idx];
                }
            }
            #pragma unroll
            for (int off = 32; off >= 1; off >>= 1)
                s0 += __shfl_xor(s0, off);
            if (lane == 0)
                u_lds[rr] = (1.0f / OT_N) / (s0 + OT_STAB);
        }
        __syncthreads();   // u_lds ready for next phase 1 / final pass
    }

    // ---- Final: P = u_i * K_ij * v_j and loss over own rows ----
    float lacc = 0.0f;
    const float vj = v_lds[j];
    for (int i = 0; i < OT_ROWS / 2; ++i) {
        const int lr = h * (OT_ROWS / 2) + i;          // local row
        const size_t off = batchOff + (size_t)(r0 + lr) * OT_M + j;
        float kv;
        if (PRE) kv = __half2float(K[off]);
        else     kv = __expf(-20.0f * Cg[off]);
        float p = u_lds[lr] * kv * vj;
        Pout[off] = p;
        lacc += p * Cg[off];
    }
    sp[t] = lacc;
    __syncthreads();
    #pragma unroll
    for (int s = OT_T / 2; s >= 64; s >>= 1) {
        if (t < s) sp[t] += sp[t + s];
        __syncthreads();
    }
    if (t < 64) {
        float rsum = sp[t];
        #pragma unroll
        for (int off = 32; off >= 1; off >>= 1) rsum += __shfl_xor(rsum, off);
        if (t == 0) atomicAdd(&lossOut[b], rsum);
    }
}

extern "C" void kernel_launch(void* const* d_in, const int* in_sizes, int n_in,
                              void* d_out, int out_size, void* d_ws, size_t ws_size,
                              hipStream_t stream) {
    const float* C = (const float*)d_in[0];
    float* P = (float*)d_out;
    float* loss = (float*)d_out + (size_t)OT_B * OT_N * OT_M;

    // ws layout: parity-double-buffered partials, counters, fp16 K
    size_t off = 0;
    float* partial = (float*)((char*)d_ws + off);
    off += (size_t)2 * OT_B * OT_NWG * OT_M * sizeof(float);   // 1 MB
    int* counters = (int*)((char*)d_ws + off);
    off += (size_t)OT_B * 32 * sizeof(int);                    // 8 KB
    off = (off + 255) & ~(size_t)255;
    __half* Kh = (__half*)((char*)d_ws + off);
    const size_t kElems = (size_t)OT_B * OT_N * OT_M;
    const size_t needed = off + kElems * sizeof(__half);       // ~34.6 MB

    hipMemsetAsync(counters, 0, (size_t)OT_B * 32 * sizeof(int), stream);
    hipMemsetAsync(loss, 0, (size_t)OT_B * sizeof(float), stream);

    if (ws_size >= needed) {
        ot_precompute_K<<<1024, 256, 0, stream>>>(C, (__half2*)Kh, (int)(kElems / 2));
        ot_sinkhorn<true><<<OT_B * OT_NWG, OT_T, 0, stream>>>(Kh, C, P, loss,
                                                              partial, counters);
    } else {
        ot_sinkhorn<false><<<OT_B * OT_NWG, OT_T, 0, stream>>>(nullptr, C, P, loss,
                                                               partial, counters);
    }
}

// Round 5
// 383.220 us; speedup vs baseline: 6.7140x; 1.9514x over previous
//
#include <hip/hip_runtime.h>
#include <hip/hip_fp16.h>

#define OT_B 64
#define OT_N 512
#define OT_M 512
#define OT_ITERS 50
#define OT_STAB 1e-8f
#define OT_NWG 4                     // workgroups cooperating per batch
#define OT_ROWS 128                  // rows owned per WG
#define OT_T 1024                    // threads per WG
#define KLDS_BYTES (OT_ROWS * 128 * sizeof(uint2))   // 128 KiB: [128 rows][128 uint2]

// group barrier: release add + relaxed spin; all cross-WG data via agent atomics
__device__ __forceinline__ void group_barrier(int* cnt, int target) {
    __syncthreads();
    if (threadIdx.x == 0) {
        __hip_atomic_fetch_add(cnt, 1, __ATOMIC_RELEASE, __HIP_MEMORY_SCOPE_AGENT);
        while (__hip_atomic_load(cnt, __ATOMIC_RELAXED, __HIP_MEMORY_SCOPE_AGENT) < target)
            __builtin_amdgcn_s_sleep(2);
        asm volatile("" ::: "memory");
    }
    __syncthreads();
}

// Sinkhorn with LDS-resident fp16 K-slice. 4 WGs x 1024 threads per batch.
// LDS K layout: row r, dword-pair p in [0,128): Klds[r*128 + (p ^ (r&15))]
//   -> phase-1 (col access, lanes vary p): 64 distinct pairs, banks balanced
//   -> phase-2 (row access, lanes vary r): 16 addr groups x 4-lane broadcast, balanced
__global__ __launch_bounds__(OT_T, 1) void ot_sinkhorn_lds(
        const float* __restrict__ Cg,
        float* __restrict__ Pout,
        float* __restrict__ lossOut,
        float* __restrict__ partial,   // [2][B][NWG][M] floats
        int* __restrict__ counters)    // [B][32]
{
    extern __shared__ __align__(16) unsigned char smem[];
    uint2* __restrict__ Klds = (uint2*)smem;            // 128 KiB
    __shared__ __align__(16) float4 sp4[OT_T];          // 16 KiB scratch (reused as float[4096])
    __shared__ __align__(16) float v_lds[OT_M];
    __shared__ float u_lds[OT_ROWS];

    const int b = blockIdx.x & (OT_B - 1);   // batch
    const int g = blockIdx.x >> 6;           // group member 0..3
    const int t = threadIdx.x;
    const int r0 = g * OT_ROWS;

    const size_t sliceOff = ((size_t)b * OT_N + r0) * OT_M;
    const float4* C4 = (const float4*)(Cg + sliceOff);
    float4* P4 = (float4*)(Pout + sliceOff);
    int* cnt = counters + b * 32;
    float* spf = (float*)sp4;

    // ---- stage: K = exp(-C/eps) fp16, swizzled into LDS (C read once) ----
    if (t < OT_ROWS) u_lds[t] = 1.0f / OT_N;
    #pragma unroll
    for (int ch = 0; ch < 16; ++ch) {
        int idx = ch * OT_T + t;             // float4 index in slice (coalesced)
        int r = idx >> 7, c4 = idx & 127;
        float4 c = C4[idx];
        __half2 h0 = __floats2half2_rn(__expf(-20.f * c.x), __expf(-20.f * c.y));
        __half2 h1 = __floats2half2_rn(__expf(-20.f * c.z), __expf(-20.f * c.w));
        uint2 w;
        w.x = *(unsigned*)&h0;
        w.y = *(unsigned*)&h1;
        Klds[r * 128 + (c4 ^ (r & 15))] = w;
    }
    __syncthreads();

    const int p1 = t & 127;        // phase1/final: owned col-quad (cols 4p1..4p1+3)
    const int q1 = t >> 7;         // phase1/final: row-group of 16
    const int r2 = t & 127;        // phase2: owned row
    const int q2 = t >> 7;         // phase2: col-group of 64

    for (int it = 0; it < OT_ITERS; ++it) {
        float* buf = partial + ((size_t)(it & 1) * OT_B + b) * (OT_NWG * OT_M);

        // ---- phase 1: partial column sums over 16 rows per thread ----
        float4 acc = {0.f, 0.f, 0.f, 0.f};
        #pragma unroll
        for (int i = 0; i < 16; ++i) {
            int r = q1 * 16 + i;
            uint2 k4 = Klds[r * 128 + (p1 ^ (r & 15))];
            float2 a  = __half22float2(*(__half2*)&k4.x);
            float2 b2 = __half22float2(*(__half2*)&k4.y);
            float uu = u_lds[r];
            acc.x += a.x * uu;  acc.y += a.y * uu;
            acc.z += b2.x * uu; acc.w += b2.y * uu;
        }
        sp4[t] = acc;
        __syncthreads();
        if (t < 128) {
            float4 s = sp4[t];
            #pragma unroll
            for (int w = 1; w < 8; ++w) {
                float4 x = sp4[w * 128 + t];
                s.x += x.x; s.y += x.y; s.z += x.z; s.w += x.w;
            }
            float* dst = &buf[g * OT_M + 4 * t];
            __hip_atomic_store(dst + 0, s.x, __ATOMIC_RELAXED, __HIP_MEMORY_SCOPE_AGENT);
            __hip_atomic_store(dst + 1, s.y, __ATOMIC_RELAXED, __HIP_MEMORY_SCOPE_AGENT);
            __hip_atomic_store(dst + 2, s.z, __ATOMIC_RELAXED, __HIP_MEMORY_SCOPE_AGENT);
            __hip_atomic_store(dst + 3, s.w, __ATOMIC_RELAXED, __HIP_MEMORY_SCOPE_AGENT);
        }

        group_barrier(cnt, OT_NWG * (it + 1));   // the only barrier per iteration

        // ---- phase 2a: v from the 4 WG partials (redundant per WG) ----
        if (t < OT_M) {
            float s = OT_STAB;
            #pragma unroll
            for (int w = 0; w < OT_NWG; ++w)
                s += __hip_atomic_load(&buf[w * OT_M + t], __ATOMIC_RELAXED,
                                       __HIP_MEMORY_SCOPE_AGENT);
            v_lds[t] = (1.0f / OT_M) / s;
        }
        __syncthreads();

        // ---- phase 2b: row dot-products, 64 cols per thread ----
        {
            float a2 = 0.f;
            const float4* v4 = (const float4*)v_lds;
            #pragma unroll
            for (int i = 0; i < 16; ++i) {
                int pp = q2 * 16 + i;
                uint2 k4 = Klds[r2 * 128 + (pp ^ (r2 & 15))];
                float2 a  = __half22float2(*(__half2*)&k4.x);
                float2 b2 = __half22float2(*(__half2*)&k4.y);
                float4 vv = v4[pp];                    // broadcast across wave
                a2 += a.x * vv.x + a.y * vv.y + b2.x * vv.z + b2.y * vv.w;
            }
            spf[t] = a2;
        }
        __syncthreads();
        if (t < 128) {
            float s = 0.f;
            #pragma unroll
            for (int w = 0; w < 8; ++w) s += spf[w * 128 + t];
            u_lds[t] = (1.0f / OT_N) / (s + OT_STAB);
        }
        __syncthreads();
    }

    // ---- final: P = u*K*v, loss = sum(P*C) over own rows ----
    float lacc = 0.f;
    {
        const float4* v4 = (const float4*)v_lds;
        const float4 vv = v4[p1];
        #pragma unroll
        for (int i = 0; i < 16; ++i) {
            int r = q1 * 16 + i;
            uint2 k4 = Klds[r * 128 + (p1 ^ (r & 15))];
            float2 a  = __half22float2(*(__half2*)&k4.x);
            float2 b2 = __half22float2(*(__half2*)&k4.y);
            float uu = u_lds[r];
            int idx = r * 128 + p1;
            float4 c = C4[idx];
            float4 pv;
            pv.x = uu * a.x * vv.x;  pv.y = uu * a.y * vv.y;
            pv.z = uu * b2.x * vv.z; pv.w = uu * b2.y * vv.w;
            P4[idx] = pv;
            lacc += pv.x * c.x + pv.y * c.y + pv.z * c.z + pv.w * c.w;
        }
    }
    __syncthreads();
    spf[t] = lacc;
    __syncthreads();
    #pragma unroll
    for (int s = OT_T / 2; s >= 64; s >>= 1) {
        if (t < s) spf[t] += spf[t + s];
        __syncthreads();
    }
    if (t < 64) {
        float rsum = spf[t];
        #pragma unroll
        for (int off = 32; off >= 1; off >>= 1) rsum += __shfl_xor(rsum, off);
        if (t == 0) atomicAdd(&lossOut[b], rsum);
    }
}

extern "C" void kernel_launch(void* const* d_in, const int* in_sizes, int n_in,
                              void* d_out, int out_size, void* d_ws, size_t ws_size,
                              hipStream_t stream) {
    const float* C = (const float*)d_in[0];
    float* P = (float*)d_out;
    float* loss = (float*)d_out + (size_t)OT_B * OT_N * OT_M;

    // ws layout: parity-double-buffered partials + counters (no K workspace needed)
    size_t off = 0;
    float* partial = (float*)((char*)d_ws + off);
    off += (size_t)2 * OT_B * OT_NWG * OT_M * sizeof(float);   // 1 MB
    int* counters = (int*)((char*)d_ws + off);

    hipMemsetAsync(counters, 0, (size_t)OT_B * 32 * sizeof(int), stream);
    hipMemsetAsync(loss, 0, (size_t)OT_B * sizeof(float), stream);

    // allow 128 KiB dynamic LDS (gfx950 has 160 KiB/CU)
    hipFuncSetAttribute((const void*)ot_sinkhorn_lds,
                        hipFuncAttributeMaxDynamicSharedMemorySize, KLDS_BYTES);

    ot_sinkhorn_lds<<<OT_B * OT_NWG, OT_T, KLDS_BYTES, stream>>>(C, P, loss,
                                                                 partial, counters);
}